// Round 1
// baseline (171.665 us; speedup 1.0000x reference)
//
#include <hip/hip_runtime.h>

// Problem constants (B, Lq, Lk, D, C, KW) = (8, 1024, 1024, 512, 512, 3)
#define KW_ 3

typedef __attribute__((ext_vector_type(8))) short s8vec;    // 8 x bf16 (4 VGPRs)
typedef __attribute__((ext_vector_type(4))) float floatx4;  // MFMA accumulator

__device__ __forceinline__ unsigned short f2bf(float f) {
    union { float f; unsigned u; } v; v.f = f;
    unsigned r = (v.u + 0x7FFFu + ((v.u >> 16) & 1u)) >> 16;
    return (unsigned short)r;
}

__device__ __forceinline__ void gl2lds16(const void* g, void* l) {
    __builtin_amdgcn_global_load_lds(
        (__attribute__((address_space(1))) void*)(g),
        (__attribute__((address_space(3))) void*)(l), 16, 0, 0);
}

// ---- fp32 -> bf16 bulk convert: each thread handles 8 floats -> 16B out ----
__global__ void cvt8(const float* __restrict__ in, unsigned short* __restrict__ out, int n8) {
    int t = blockIdx.x * blockDim.x + threadIdx.x;
    if (t >= n8) return;
    const float4* p = (const float4*)in + 2 * (size_t)t;
    float4 a = p[0], b = p[1];
    union { unsigned short s[8]; uint4 v; } o;
    o.s[0] = f2bf(a.x); o.s[1] = f2bf(a.y); o.s[2] = f2bf(a.z); o.s[3] = f2bf(a.w);
    o.s[4] = f2bf(b.x); o.s[5] = f2bf(b.y); o.s[6] = f2bf(b.z); o.s[7] = f2bf(b.w);
    ((uint4*)out)[t] = o.v;
}

// ---- W_kernel (512 x 1536, d-major) -> Wt[w][c][d] bf16 (1536 x 512) ----
__global__ void prep_Wt(const float* __restrict__ W, unsigned short* __restrict__ Wt) {
    __shared__ float lds[32][33];
    int cw0 = blockIdx.x * 32, d0 = blockIdx.y * 32;
    int tx = threadIdx.x, ty = threadIdx.y;
    lds[ty][tx] = W[(size_t)(d0 + ty) * 1536 + cw0 + tx];
    __syncthreads();
    int cw = cw0 + ty;                 // cw = c*3 + w
    int c = cw / 3, w = cw % 3;
    Wt[((size_t)(w * 512 + c)) * 512 + d0 + tx] = f2bf(lds[tx][ty]);
}

// ---- bias[b*1024+i] = q[b,i,:] . W_bias + b_bias ; one wave per row ----
__global__ void bias_kernel(const float* __restrict__ q, const float* __restrict__ Wb,
                            const float* __restrict__ b_bias, float* __restrict__ biasb) {
    int row  = blockIdx.x * 4 + (threadIdx.x >> 6);
    int lane = threadIdx.x & 63;
    const float4* qr = (const float4*)(q + (size_t)row * 512) + lane * 2;
    const float4* wb = (const float4*)Wb + lane * 2;
    float4 a0 = qr[0], a1 = qr[1], b0 = wb[0], b1 = wb[1];
    float s = a0.x*b0.x + a0.y*b0.y + a0.z*b0.z + a0.w*b0.w
            + a1.x*b1.x + a1.y*b1.y + a1.z*b1.z + a1.w*b1.w;
    #pragma unroll
    for (int off = 32; off > 0; off >>= 1) s += __shfl_down(s, off);
    if (lane == 0) biasb[row] = s + b_bias[0];
}

// ---- Phase A: G[b][w][i][c] = bf16( q_bf(8192x512) @ Wt(1536x512)^T + b_kernel ) ----
__global__ __launch_bounds__(256) void gemm_A(const unsigned short* __restrict__ Abf,
                                              const unsigned short* __restrict__ Bbf,
                                              const float* __restrict__ b_kernel,
                                              unsigned short* __restrict__ G) {
    __shared__ unsigned short lds_a[128 * 32];
    __shared__ unsigned short lds_b[128 * 32];
    int i0 = blockIdx.y * 128;
    int n0 = blockIdx.x * 128;
    int tid = threadIdx.x, wid = tid >> 6, lane = tid & 63;
    int wm = wid >> 1, wn = wid & 1;
    floatx4 acc[4][4] = {};

    for (int kk = 0; kk < 512; kk += 32) {
        #pragma unroll
        for (int s = 0; s < 2; ++s) {
            int t = wid * 2 + s;   // 0..7, wave-uniform
            const unsigned short* ga = Abf + (size_t)(i0 + t * 16 + (lane >> 2)) * 512 + kk + (lane & 3) * 8;
            gl2lds16(ga, (char*)lds_a + t * 1024);
            const unsigned short* gb = Bbf + (size_t)(n0 + t * 16 + (lane >> 2)) * 512 + kk + (lane & 3) * 8;
            gl2lds16(gb, (char*)lds_b + t * 1024);
        }
        __syncthreads();
        int ra = lane & 15, q8 = (lane >> 4) * 8;
        s8vec af[4], bf_[4];
        #pragma unroll
        for (int mi = 0; mi < 4; mi++)
            af[mi] = *(const s8vec*)(lds_a + (wm * 64 + mi * 16 + ra) * 32 + q8);
        #pragma unroll
        for (int ni = 0; ni < 4; ni++)
            bf_[ni] = *(const s8vec*)(lds_b + (wn * 64 + ni * 16 + ra) * 32 + q8);
        #pragma unroll
        for (int mi = 0; mi < 4; mi++)
            #pragma unroll
            for (int ni = 0; ni < 4; ni++)
                acc[mi][ni] = __builtin_amdgcn_mfma_f32_16x16x32_bf16(af[mi], bf_[ni], acc[mi][ni], 0, 0, 0);
        __syncthreads();
    }

    int cl = lane & 15, qd = lane >> 4;
    #pragma unroll
    for (int mi = 0; mi < 4; mi++) {
        #pragma unroll
        for (int ni = 0; ni < 4; ni++) {
            int n_all = n0 + wn * 64 + ni * 16 + cl;   // w*512 + c
            int c = n_all & 511, w = n_all >> 9;
            float bk = b_kernel[c * 3 + w];
            #pragma unroll
            for (int r = 0; r < 4; r++) {
                int i_g = i0 + wm * 64 + mi * 16 + qd * 4 + r;
                int b = i_g >> 10, ii = i_g & 1023;
                G[((size_t)((b * 3 + w) * 1024 + ii)) * 512 + c] = f2bf(acc[mi][ni][r] + bk);
            }
        }
    }
}

// ---- Phase B: out[b,i,j] = sum_w sum_c G[b,w,i,c] * k[b, j+w-1, c] + bias[b,i] + bias_b ----
__global__ __launch_bounds__(256) void gemm_B(const unsigned short* __restrict__ G,
                                              const unsigned short* __restrict__ kbf,
                                              const float* __restrict__ biasb,
                                              const float* __restrict__ bias_b,
                                              float* __restrict__ out) {
    __shared__ unsigned short lds_a[3 * 128 * 32];  // [w][i][c]
    __shared__ unsigned short lds_k[130 * 32];      // rows j0-1 .. j0+128
    int b  = blockIdx.z;
    int i0 = blockIdx.y * 128;
    int j0 = blockIdx.x * 128;
    int tid = threadIdx.x, wid = tid >> 6, lane = tid & 63;
    int wm = wid >> 1, wn = wid & 1;
    floatx4 acc[4][4] = {};
    const unsigned short* Gb = G + (size_t)b * 3 * 1024 * 512;
    const unsigned short* kb = kbf + (size_t)b * 1024 * 512;
    float bb = bias_b[0];

    for (int kk = 0; kk < 512; kk += 32) {
        // stage 3 A-tiles (G_w): 24 wave-instructions, 6 per wave
        #pragma unroll
        for (int s = 0; s < 6; ++s) {
            int t = s * 4 + wid;                    // 0..23, wave-uniform
            int w = t >> 3, iblk = (t & 7) * 16;
            const unsigned short* ga = Gb + (size_t)(w * 1024 + i0 + iblk + (lane >> 2)) * 512
                                          + kk + (lane & 3) * 8;
            gl2lds16(ga, (char*)lds_a + t * 1024);
        }
        // stage k window rows j0-1 .. j0+128 (130 rows x 64B), zero at borders
        for (int ch = tid; ch < 520; ch += 256) {
            int r = ch >> 2, cb = ch & 3;
            int j = j0 - 1 + r;
            uint4 v = make_uint4(0u, 0u, 0u, 0u);
            if (j >= 0 && j < 1024)
                v = *(const uint4*)(kb + (size_t)j * 512 + kk + cb * 8);
            *(uint4*)((char*)lds_k + ch * 16) = v;
        }
        __syncthreads();
        int ra = lane & 15, q8 = (lane >> 4) * 8;
        #pragma unroll
        for (int w = 0; w < 3; ++w) {
            s8vec af[4], bfr[4];
            #pragma unroll
            for (int mi = 0; mi < 4; mi++)
                af[mi] = *(const s8vec*)(lds_a + w * 4096 + (wm * 64 + mi * 16 + ra) * 32 + q8);
            #pragma unroll
            for (int ni = 0; ni < 4; ni++) {
                int rr = wn * 64 + ni * 16 + ra + w;   // 0..129
                bfr[ni] = *(const s8vec*)(lds_k + rr * 32 + q8);
            }
            #pragma unroll
            for (int mi = 0; mi < 4; mi++)
                #pragma unroll
                for (int ni = 0; ni < 4; ni++)
                    acc[mi][ni] = __builtin_amdgcn_mfma_f32_16x16x32_bf16(af[mi], bfr[ni], acc[mi][ni], 0, 0, 0);
        }
        __syncthreads();
    }

    int cl = lane & 15, qd = lane >> 4;
    #pragma unroll
    for (int mi = 0; mi < 4; mi++) {
        #pragma unroll
        for (int r = 0; r < 4; r++) {
            int i_loc = wm * 64 + mi * 16 + qd * 4 + r;
            float bv = biasb[b * 1024 + i0 + i_loc] + bb;
            #pragma unroll
            for (int ni = 0; ni < 4; ni++) {
                int j_loc = wn * 64 + ni * 16 + cl;
                out[((size_t)(b * 1024 + i0 + i_loc)) * 1024 + j0 + j_loc] = acc[mi][ni][r] + bv;
            }
        }
    }
}

extern "C" void kernel_launch(void* const* d_in, const int* in_sizes, int n_in,
                              void* d_out, int out_size, void* d_ws, size_t ws_size,
                              hipStream_t stream) {
    const float* q        = (const float*)d_in[0];  // (8,1024,512)
    const float* k        = (const float*)d_in[1];  // (8,1024,512)
    const float* W_kernel = (const float*)d_in[2];  // (512,1536)
    const float* b_kernel = (const float*)d_in[3];  // (1536,)
    const float* W_bias   = (const float*)d_in[4];  // (512,1)
    const float* b_bias   = (const float*)d_in[5];  // (1,)
    const float* bias_b   = (const float*)d_in[6];  // (1,)
    float* out = (float*)d_out;                     // (8,1024,1024)

    // workspace carve (bytes): q_bf 8M | k_bf 8M | Wt 1.5M | G 24M | bias 32K
    char* ws = (char*)d_ws;
    unsigned short* q_bf = (unsigned short*)(ws);
    unsigned short* k_bf = (unsigned short*)(ws + 8388608);
    unsigned short* Wt   = (unsigned short*)(ws + 2 * 8388608);
    unsigned short* G    = (unsigned short*)(ws + 2 * 8388608 + 1572864);
    float*          bsb  = (float*)(ws + 2 * 8388608 + 1572864 + 25165824);

    const int n8 = (8 * 1024 * 512) / 8;  // 524288
    cvt8<<<(n8 + 255) / 256, 256, 0, stream>>>(q, q_bf, n8);
    cvt8<<<(n8 + 255) / 256, 256, 0, stream>>>(k, k_bf, n8);
    prep_Wt<<<dim3(48, 16), dim3(32, 32), 0, stream>>>(W_kernel, Wt);
    bias_kernel<<<2048, 256, 0, stream>>>(q, W_bias, b_bias, bsb);
    gemm_A<<<dim3(12, 64), 256, 0, stream>>>(q_bf, Wt, b_kernel, G);
    gemm_B<<<dim3(8, 8, 8), 256, 0, stream>>>(G, k_bf, bsb, bias_b, out);
}

// Round 3
// 171.476 us; speedup vs baseline: 1.0011x; 1.0011x over previous
//
#include <hip/hip_runtime.h>

// (B, Lq, Lk, D, C, KW) = (8, 1024, 1024, 512, 512, 3)

typedef __attribute__((ext_vector_type(8))) short s8vec;    // 8 x bf16 (4 VGPRs)
typedef __attribute__((ext_vector_type(4))) float floatx4;  // MFMA accumulator

__device__ __forceinline__ unsigned short f2bf(float f) {
    union { float f; unsigned u; } v; v.f = f;
    unsigned r = (v.u + 0x7FFFu + ((v.u >> 16) & 1u)) >> 16;
    return (unsigned short)r;
}

__device__ __forceinline__ void gl2lds16(const void* g, void* l) {
    __builtin_amdgcn_global_load_lds(
        (__attribute__((address_space(1))) void*)(g),
        (__attribute__((address_space(3))) void*)(l), 16, 0, 0);
}

// ---- convert q -> q_bf, k -> kp (padded: per b rows 0..1027, row p = k[p-1],
//      rows 0,1025,1026,1027 zero), all in one launch ----
__global__ void cvt_all(const float* __restrict__ q, const float* __restrict__ k,
                        unsigned short* __restrict__ qbf, unsigned short* __restrict__ kp) {
    int t = blockIdx.x * blockDim.x + threadIdx.x;
    if (t < 524288) {                       // q: 8*1024*512 / 8
        const float4* p = (const float4*)q + 2 * (size_t)t;
        float4 a = p[0], b = p[1];
        union { unsigned short s[8]; uint4 v; } o;
        o.s[0]=f2bf(a.x); o.s[1]=f2bf(a.y); o.s[2]=f2bf(a.z); o.s[3]=f2bf(a.w);
        o.s[4]=f2bf(b.x); o.s[5]=f2bf(b.y); o.s[6]=f2bf(b.z); o.s[7]=f2bf(b.w);
        ((uint4*)qbf)[t] = o.v;
    } else if (t < 1048576) {               // k -> padded kp
        int e8 = t - 524288;
        size_t e = (size_t)e8 * 8;
        int b = e8 >> 16;                   // e8 / 65536
        int j = (e8 >> 6) & 1023;           // (e/512) % 1024
        int c = (e8 & 63) * 8;
        const float4* p = (const float4*)(k + e);
        float4 a = p[0], bb = p[1];
        union { unsigned short s[8]; uint4 v; } o;
        o.s[0]=f2bf(a.x); o.s[1]=f2bf(a.y); o.s[2]=f2bf(a.z); o.s[3]=f2bf(a.w);
        o.s[4]=f2bf(bb.x); o.s[5]=f2bf(bb.y); o.s[6]=f2bf(bb.z); o.s[7]=f2bf(bb.w);
        *(uint4*)(kp + ((size_t)(b * 1028 + j + 1) * 512 + c)) = o.v;
    } else if (t < 1050624) {               // zero pad rows: 8b * 4rows * 64 chunks
        int z = t - 1048576;
        int b = z >> 8, r = (z >> 6) & 3, ch = z & 63;
        int row = r ? (1024 + r) : 0;
        *(uint4*)(kp + ((size_t)(b * 1028 + row) * 512 + ch * 8)) = make_uint4(0u,0u,0u,0u);
    }
}

// ---- W_kernel (512 x 1536, d-major) -> Wt[w][c][d] bf16 (1536 x 512) ----
__global__ void prep_Wt(const float* __restrict__ W, unsigned short* __restrict__ Wt) {
    __shared__ float lds[32][33];
    int cw0 = blockIdx.x * 32, d0 = blockIdx.y * 32;
    int tx = threadIdx.x, ty = threadIdx.y;
    lds[ty][tx] = W[(size_t)(d0 + ty) * 1536 + cw0 + tx];
    __syncthreads();
    int cw = cw0 + ty;                 // cw = c*3 + w
    int c = cw / 3, w = cw % 3;
    Wt[((size_t)(w * 512 + c)) * 512 + d0 + tx] = f2bf(lds[tx][ty]);
}

// ---- bias[b*1024+i] = q[b,i,:] . W_bias + b_bias ; one wave per row ----
__global__ void bias_kernel(const float* __restrict__ q, const float* __restrict__ Wb,
                            const float* __restrict__ b_bias, float* __restrict__ biasb) {
    int row  = blockIdx.x * 4 + (threadIdx.x >> 6);
    int lane = threadIdx.x & 63;
    const float4* qr = (const float4*)(q + (size_t)row * 512) + lane * 2;
    const float4* wb = (const float4*)Wb + lane * 2;
    float4 a0 = qr[0], a1 = qr[1], b0 = wb[0], b1 = wb[1];
    float s = a0.x*b0.x + a0.y*b0.y + a0.z*b0.z + a0.w*b0.w
            + a1.x*b1.x + a1.y*b1.y + a1.z*b1.z + a1.w*b1.w;
    #pragma unroll
    for (int off = 32; off > 0; off >>= 1) s += __shfl_down(s, off);
    if (lane == 0) biasb[row] = s + b_bias[0];
}

// ---- Phase A: G[b][w][i][c] = bf16( q_bf(8192x512) @ Wt(1536x512)^T + b_kernel )
//      64m x 128n tiles, grid (12, 128), 4 waves split over n ----
__global__ __launch_bounds__(256) void gemm_A(const unsigned short* __restrict__ Abf,
                                              const unsigned short* __restrict__ Bbf,
                                              const float* __restrict__ b_kernel,
                                              unsigned short* __restrict__ G) {
    __shared__ unsigned short lds_a[64 * 32];
    __shared__ unsigned short lds_b[128 * 32];
    int n0 = blockIdx.x * 128;
    int i0 = blockIdx.y * 64;
    int tid = threadIdx.x, wid = tid >> 6, lane = tid & 63;
    int wn = wid;
    floatx4 acc[4][2] = {};

    for (int kk = 0; kk < 512; kk += 32) {
        #pragma unroll
        for (int s = 0; s < 3; ++s) {
            int t = wid * 3 + s;   // 0..11, wave-uniform; 16 rows per inst
            if (t < 4) {
                const unsigned short* ga = Abf + (size_t)(i0 + t * 16 + (lane >> 2)) * 512 + kk + (lane & 3) * 8;
                gl2lds16(ga, (char*)lds_a + t * 1024);
            } else {
                int u = t - 4;
                const unsigned short* gb = Bbf + (size_t)(n0 + u * 16 + (lane >> 2)) * 512 + kk + (lane & 3) * 8;
                gl2lds16(gb, (char*)lds_b + u * 1024);
            }
        }
        __syncthreads();
        int ra = lane & 15, q8 = (lane >> 4) * 8;
        s8vec af[4], bf_[2];
        #pragma unroll
        for (int mi = 0; mi < 4; mi++)
            af[mi] = *(const s8vec*)(lds_a + (mi * 16 + ra) * 32 + q8);
        #pragma unroll
        for (int ni = 0; ni < 2; ni++)
            bf_[ni] = *(const s8vec*)(lds_b + (wn * 32 + ni * 16 + ra) * 32 + q8);
        #pragma unroll
        for (int mi = 0; mi < 4; mi++)
            #pragma unroll
            for (int ni = 0; ni < 2; ni++)
                acc[mi][ni] = __builtin_amdgcn_mfma_f32_16x16x32_bf16(af[mi], bf_[ni], acc[mi][ni], 0, 0, 0);
        __syncthreads();
    }

    int cl = lane & 15, qd = lane >> 4;
    #pragma unroll
    for (int mi = 0; mi < 4; mi++) {
        #pragma unroll
        for (int ni = 0; ni < 2; ni++) {
            int n_all = n0 + wn * 32 + ni * 16 + cl;   // w*512 + c
            int c = n_all & 511, w = n_all >> 9;
            float bk = b_kernel[c * 3 + w];
            #pragma unroll
            for (int r = 0; r < 4; r++) {
                int i_g = i0 + mi * 16 + qd * 4 + r;
                int b = i_g >> 10, ii = i_g & 1023;
                G[((size_t)((b * 3 + w) * 1024 + ii)) * 512 + c] = f2bf(acc[mi][ni][r] + bk);
            }
        }
    }
}

// ---- Phase B: out[b,i,j] = sum_w sum_c G[b,w,i,c] * kp[b, j+w, c] + bias[b,i] + bias_b
//      64i x 128j tiles, grid (8, 16, 8), 4 waves split over j; kp is zero-padded ----
__global__ __launch_bounds__(256) void gemm_B(const unsigned short* __restrict__ G,
                                              const unsigned short* __restrict__ kp,
                                              const float* __restrict__ biasb,
                                              const float* __restrict__ bias_b,
                                              float* __restrict__ out) {
    __shared__ unsigned short lds_a[3 * 64 * 32];   // [w][i][c]  12 KB
    __shared__ unsigned short lds_k[144 * 32];      // 9 chunks x 16 rows  9 KB (rows 130..143 unused)
    int b  = blockIdx.z;
    int i0 = blockIdx.y * 64;
    int j0 = blockIdx.x * 128;
    int tid = threadIdx.x, wid = tid >> 6, lane = tid & 63;
    int wn = wid;
    floatx4 acc[4][2] = {};
    const unsigned short* Gb  = G  + (size_t)b * 3 * 1024 * 512;
    const unsigned short* kpb = kp + (size_t)b * 1028 * 512;
    float bb = bias_b[0];

    for (int kk = 0; kk < 512; kk += 32) {
        // stage A (3 x 64 rows): 12 wave-uniform insts (16 rows each), 3 per wave
        #pragma unroll
        for (int s = 0; s < 3; ++s) {
            int t = wid * 3 + s;                    // 0..11; w = t/4, 16-row chunk = t%4
            int w = t >> 2, chunk = t & 3;
            const unsigned short* ga = Gb + (size_t)(w * 1024 + i0 + chunk * 16 + (lane >> 2)) * 512
                                          + kk + (lane & 3) * 8;
            gl2lds16(ga, (char*)lds_a + t * 1024);
        }
        // stage padded k rows j0 .. j0+143: 9 insts x 16 rows (need j0..j0+129)
        #pragma unroll
        for (int s = 0; s < 3; ++s) {
            int t = s * 4 + wid;                    // 0..11, use t<9
            if (t < 9) {
                const unsigned short* gk = kpb + (size_t)(j0 + t * 16 + (lane >> 2)) * 512
                                               + kk + (lane & 3) * 8;
                gl2lds16(gk, (char*)lds_k + t * 1024);
            }
        }
        __syncthreads();
        int ra = lane & 15, q8 = (lane >> 4) * 8;
        #pragma unroll
        for (int w = 0; w < 3; ++w) {
            s8vec af[4], bfr[2];
            #pragma unroll
            for (int mi = 0; mi < 4; mi++)
                af[mi] = *(const s8vec*)(lds_a + (w * 64 + mi * 16 + ra) * 32 + q8);
            #pragma unroll
            for (int ni = 0; ni < 2; ni++) {
                int rr = wn * 32 + ni * 16 + ra + w;   // lds row r = kp row j0+r = k row j0+r-1
                bfr[ni] = *(const s8vec*)(lds_k + rr * 32 + q8);
            }
            #pragma unroll
            for (int mi = 0; mi < 4; mi++)
                #pragma unroll
                for (int ni = 0; ni < 2; ni++)
                    acc[mi][ni] = __builtin_amdgcn_mfma_f32_16x16x32_bf16(af[mi], bfr[ni], acc[mi][ni], 0, 0, 0);
        }
        __syncthreads();
    }

    int cl = lane & 15, qd = lane >> 4;
    #pragma unroll
    for (int mi = 0; mi < 4; mi++) {
        #pragma unroll
        for (int r = 0; r < 4; r++) {
            int i_loc = mi * 16 + qd * 4 + r;
            float bv = biasb[b * 1024 + i0 + i_loc] + bb;
            #pragma unroll
            for (int ni = 0; ni < 2; ni++) {
                int j_loc = wn * 32 + ni * 16 + cl;
                out[((size_t)(b * 1024 + i0 + i_loc)) * 1024 + j0 + j_loc] = acc[mi][ni][r] + bv;
            }
        }
    }
}

extern "C" void kernel_launch(void* const* d_in, const int* in_sizes, int n_in,
                              void* d_out, int out_size, void* d_ws, size_t ws_size,
                              hipStream_t stream) {
    const float* q        = (const float*)d_in[0];  // (8,1024,512)
    const float* k        = (const float*)d_in[1];  // (8,1024,512)
    const float* W_kernel = (const float*)d_in[2];  // (512,1536)
    const float* b_kernel = (const float*)d_in[3];  // (1536,)
    const float* W_bias   = (const float*)d_in[4];  // (512,1)
    const float* b_bias   = (const float*)d_in[5];  // (1,)
    const float* bias_b   = (const float*)d_in[6];  // (1,)
    float* out = (float*)d_out;                     // (8,1024,1024)

    // workspace carve (bytes): q_bf 8M | kp 8.03M+16K headroom | Wt 1.5M | G 24M | bias 32K
    char* ws = (char*)d_ws;
    unsigned short* q_bf = (unsigned short*)(ws);
    unsigned short* kp   = (unsigned short*)(ws + 8388608);
    unsigned short* Wt   = (unsigned short*)(ws + 8388608 + 8421376 + 16384);
    unsigned short* G    = (unsigned short*)(ws + 8388608 + 8421376 + 16384 + 1572864);
    float*          bsb  = (float*)(ws + 8388608 + 8421376 + 16384 + 1572864 + 25165824);

    cvt_all<<<4104, 256, 0, stream>>>(q, k, q_bf, kp);
    prep_Wt<<<dim3(48, 16), dim3(32, 32), 0, stream>>>(W_kernel, Wt);
    bias_kernel<<<2048, 256, 0, stream>>>(q, W_bias, b_bias, bsb);
    gemm_A<<<dim3(12, 128), 256, 0, stream>>>(q_bf, Wt, b_kernel, G);
    gemm_B<<<dim3(8, 16, 8), 256, 0, stream>>>(G, kp, bsb, bias_b, out);
}

// Round 4
// 152.085 us; speedup vs baseline: 1.1287x; 1.1275x over previous
//
#include <hip/hip_runtime.h>

// (B, Lq, Lk, D, C, KW) = (8, 1024, 1024, 512, 512, 3)

typedef __attribute__((ext_vector_type(8))) short s8vec;    // 8 x bf16 (4 VGPRs)
typedef __attribute__((ext_vector_type(4))) float floatx4;  // MFMA accumulator

__device__ __forceinline__ unsigned short f2bf(float f) {
    union { float f; unsigned u; } v; v.f = f;
    unsigned r = (v.u + 0x7FFFu + ((v.u >> 16) & 1u)) >> 16;
    return (unsigned short)r;
}

__device__ __forceinline__ void gl2lds16(const void* g, void* l) {
    __builtin_amdgcn_global_load_lds(
        (__attribute__((address_space(1))) void*)(g),
        (__attribute__((address_space(3))) void*)(l), 16, 0, 0);
}

// ---- convert q -> q_bf, k -> kp (padded: per b rows 0..1027, row p = k[p-1],
//      rows 0,1025,1026,1027 zero), all in one launch ----
__global__ void cvt_all(const float* __restrict__ q, const float* __restrict__ k,
                        unsigned short* __restrict__ qbf, unsigned short* __restrict__ kp) {
    int t = blockIdx.x * blockDim.x + threadIdx.x;
    if (t < 524288) {                       // q: 8*1024*512 / 8
        const float4* p = (const float4*)q + 2 * (size_t)t;
        float4 a = p[0], b = p[1];
        union { unsigned short s[8]; uint4 v; } o;
        o.s[0]=f2bf(a.x); o.s[1]=f2bf(a.y); o.s[2]=f2bf(a.z); o.s[3]=f2bf(a.w);
        o.s[4]=f2bf(b.x); o.s[5]=f2bf(b.y); o.s[6]=f2bf(b.z); o.s[7]=f2bf(b.w);
        ((uint4*)qbf)[t] = o.v;
    } else if (t < 1048576) {               // k -> padded kp
        int e8 = t - 524288;
        size_t e = (size_t)e8 * 8;
        int b = e8 >> 16;                   // e8 / 65536
        int j = (e8 >> 6) & 1023;           // (e/512) % 1024
        int c = (e8 & 63) * 8;
        const float4* p = (const float4*)(k + e);
        float4 a = p[0], bb = p[1];
        union { unsigned short s[8]; uint4 v; } o;
        o.s[0]=f2bf(a.x); o.s[1]=f2bf(a.y); o.s[2]=f2bf(a.z); o.s[3]=f2bf(a.w);
        o.s[4]=f2bf(bb.x); o.s[5]=f2bf(bb.y); o.s[6]=f2bf(bb.z); o.s[7]=f2bf(bb.w);
        *(uint4*)(kp + ((size_t)(b * 1028 + j + 1) * 512 + c)) = o.v;
    } else if (t < 1050624) {               // zero pad rows: 8b * 4rows * 64 chunks
        int z = t - 1048576;
        int b = z >> 8, r = (z >> 6) & 3, ch = z & 63;
        int row = r ? (1024 + r) : 0;
        *(uint4*)(kp + ((size_t)(b * 1028 + row) * 512 + ch * 8)) = make_uint4(0u,0u,0u,0u);
    }
}

// ---- W_kernel (512 x 1536, d-major) -> Wt[w][c][d] bf16 (1536 x 512) ----
__global__ void prep_Wt(const float* __restrict__ W, unsigned short* __restrict__ Wt) {
    __shared__ float lds[32][33];
    int cw0 = blockIdx.x * 32, d0 = blockIdx.y * 32;
    int tx = threadIdx.x, ty = threadIdx.y;
    lds[ty][tx] = W[(size_t)(d0 + ty) * 1536 + cw0 + tx];
    __syncthreads();
    int cw = cw0 + ty;                 // cw = c*3 + w
    int c = cw / 3, w = cw % 3;
    Wt[((size_t)(w * 512 + c)) * 512 + d0 + tx] = f2bf(lds[tx][ty]);
}

// ---- bias[b*1024+i] = q[b,i,:] . W_bias + b_bias ; one wave per row ----
__global__ void bias_kernel(const float* __restrict__ q, const float* __restrict__ Wb,
                            const float* __restrict__ b_bias, float* __restrict__ biasb) {
    int row  = blockIdx.x * 4 + (threadIdx.x >> 6);
    int lane = threadIdx.x & 63;
    const float4* qr = (const float4*)(q + (size_t)row * 512) + lane * 2;
    const float4* wb = (const float4*)Wb + lane * 2;
    float4 a0 = qr[0], a1 = qr[1], b0 = wb[0], b1 = wb[1];
    float s = a0.x*b0.x + a0.y*b0.y + a0.z*b0.z + a0.w*b0.w
            + a1.x*b1.x + a1.y*b1.y + a1.z*b1.z + a1.w*b1.w;
    #pragma unroll
    for (int off = 32; off > 0; off >>= 1) s += __shfl_down(s, off);
    if (lane == 0) biasb[row] = s + b_bias[0];
}

// ---- Phase A: G[b][w][i][c] = bf16( q_bf(8192x512) @ Wt(1536x512)^T + b_kernel )
//      128m x 128n tiles, flat grid 768, XCD swizzle: xcd owns 8 contiguous i-blocks ----
__global__ __launch_bounds__(256) void gemm_A(const unsigned short* __restrict__ Abf,
                                              const unsigned short* __restrict__ Bbf,
                                              const float* __restrict__ b_kernel,
                                              unsigned short* __restrict__ G) {
    __shared__ unsigned short lds_a[128 * 32];
    __shared__ unsigned short lds_b[128 * 32];
    int g = blockIdx.x;                 // 0..767
    int xcd = g & 7, slot = g >> 3;     // slot 0..95
    int n_blk = slot / 8;               // 0..11
    int i_blk = xcd * 8 + (slot & 7);   // 0..63  (1 MB q-slice per XCD)
    int i0 = i_blk * 128;
    int n0 = n_blk * 128;
    int tid = threadIdx.x, wid = tid >> 6, lane = tid & 63;
    int wm = wid >> 1, wn = wid & 1;
    floatx4 acc[4][4] = {};

    for (int kk = 0; kk < 512; kk += 32) {
        #pragma unroll
        for (int s = 0; s < 2; ++s) {
            int t = wid * 2 + s;   // 0..7, wave-uniform, 16 rows per inst
            const unsigned short* ga = Abf + (size_t)(i0 + t * 16 + (lane >> 2)) * 512 + kk + (lane & 3) * 8;
            gl2lds16(ga, (char*)lds_a + t * 1024);
            const unsigned short* gb = Bbf + (size_t)(n0 + t * 16 + (lane >> 2)) * 512 + kk + (lane & 3) * 8;
            gl2lds16(gb, (char*)lds_b + t * 1024);
        }
        __syncthreads();
        int ra = lane & 15, q8 = (lane >> 4) * 8;
        s8vec af[4], bf_[4];
        #pragma unroll
        for (int mi = 0; mi < 4; mi++)
            af[mi] = *(const s8vec*)(lds_a + (wm * 64 + mi * 16 + ra) * 32 + q8);
        #pragma unroll
        for (int ni = 0; ni < 4; ni++)
            bf_[ni] = *(const s8vec*)(lds_b + (wn * 64 + ni * 16 + ra) * 32 + q8);
        #pragma unroll
        for (int mi = 0; mi < 4; mi++)
            #pragma unroll
            for (int ni = 0; ni < 4; ni++)
                acc[mi][ni] = __builtin_amdgcn_mfma_f32_16x16x32_bf16(af[mi], bf_[ni], acc[mi][ni], 0, 0, 0);
        __syncthreads();
    }

    int cl = lane & 15, qd = lane >> 4;
    #pragma unroll
    for (int mi = 0; mi < 4; mi++) {
        #pragma unroll
        for (int ni = 0; ni < 4; ni++) {
            int n_all = n0 + wn * 64 + ni * 16 + cl;   // w*512 + c
            int c = n_all & 511, w = n_all >> 9;
            float bk = b_kernel[c * 3 + w];
            #pragma unroll
            for (int r = 0; r < 4; r++) {
                int i_g = i0 + wm * 64 + mi * 16 + qd * 4 + r;
                int b = i_g >> 10, ii = i_g & 1023;
                G[((size_t)((b * 3 + w) * 1024 + ii)) * 512 + c] = f2bf(acc[mi][ni][r] + bk);
            }
        }
    }
}

// ---- Phase B: out[b,i,j] = sum_w sum_c G[b,w,i,c] * kp[b, j+w, c] + bias[b,i] + bias_b
//      64i x 128j tiles, flat grid 1024, XCD swizzle: xcd owns batch b
//      (G[b] 3MB + kp[b] 1MB resident in that XCD's 4MB L2) ----
__global__ __launch_bounds__(256) void gemm_B(const unsigned short* __restrict__ G,
                                              const unsigned short* __restrict__ kp,
                                              const float* __restrict__ biasb,
                                              const float* __restrict__ bias_b,
                                              float* __restrict__ out) {
    __shared__ unsigned short lds_a[3 * 64 * 32];   // [w][i][c]  12 KB
    __shared__ unsigned short lds_k[144 * 32];      // 9 chunks x 16 rows  9 KB (rows 130..143 unused)
    int g = blockIdx.x;                 // 0..1023
    int b = g & 7, slot = g >> 3;       // slot 0..127
    int j0 = (slot & 7) * 128;
    int i0 = (slot >> 3) * 64;
    int tid = threadIdx.x, wid = tid >> 6, lane = tid & 63;
    int wn = wid;
    floatx4 acc[4][2] = {};
    const unsigned short* Gb  = G  + (size_t)b * 3 * 1024 * 512;
    const unsigned short* kpb = kp + (size_t)b * 1028 * 512;
    float bb = bias_b[0];

    for (int kk = 0; kk < 512; kk += 32) {
        // stage A (3 x 64 rows): 12 wave-uniform insts (16 rows each), 3 per wave
        #pragma unroll
        for (int s = 0; s < 3; ++s) {
            int t = wid * 3 + s;                    // 0..11; w = t/4, 16-row chunk = t%4
            int w = t >> 2, chunk = t & 3;
            const unsigned short* ga = Gb + (size_t)(w * 1024 + i0 + chunk * 16 + (lane >> 2)) * 512
                                          + kk + (lane & 3) * 8;
            gl2lds16(ga, (char*)lds_a + t * 1024);
        }
        // stage padded k rows j0 .. j0+143: 9 insts x 16 rows (need j0..j0+129)
        #pragma unroll
        for (int s = 0; s < 3; ++s) {
            int t = s * 4 + wid;                    // 0..11, use t<9
            if (t < 9) {
                const unsigned short* gk = kpb + (size_t)(j0 + t * 16 + (lane >> 2)) * 512
                                               + kk + (lane & 3) * 8;
                gl2lds16(gk, (char*)lds_k + t * 1024);
            }
        }
        __syncthreads();
        int ra = lane & 15, q8 = (lane >> 4) * 8;
        #pragma unroll
        for (int w = 0; w < 3; ++w) {
            s8vec af[4], bfr[2];
            #pragma unroll
            for (int mi = 0; mi < 4; mi++)
                af[mi] = *(const s8vec*)(lds_a + (w * 64 + mi * 16 + ra) * 32 + q8);
            #pragma unroll
            for (int ni = 0; ni < 2; ni++) {
                int rr = wn * 32 + ni * 16 + ra + w;   // lds row r = kp row j0+r = k row j0+r-1
                bfr[ni] = *(const s8vec*)(lds_k + rr * 32 + q8);
            }
            #pragma unroll
            for (int mi = 0; mi < 4; mi++)
                #pragma unroll
                for (int ni = 0; ni < 2; ni++)
                    acc[mi][ni] = __builtin_amdgcn_mfma_f32_16x16x32_bf16(af[mi], bfr[ni], acc[mi][ni], 0, 0, 0);
        }
        __syncthreads();
    }

    int cl = lane & 15, qd = lane >> 4;
    #pragma unroll
    for (int mi = 0; mi < 4; mi++) {
        #pragma unroll
        for (int r = 0; r < 4; r++) {
            int i_loc = mi * 16 + qd * 4 + r;
            float bv = biasb[b * 1024 + i0 + i_loc] + bb;
            #pragma unroll
            for (int ni = 0; ni < 2; ni++) {
                int j_loc = wn * 32 + ni * 16 + cl;
                out[((size_t)(b * 1024 + i0 + i_loc)) * 1024 + j0 + j_loc] = acc[mi][ni][r] + bv;
            }
        }
    }
}

extern "C" void kernel_launch(void* const* d_in, const int* in_sizes, int n_in,
                              void* d_out, int out_size, void* d_ws, size_t ws_size,
                              hipStream_t stream) {
    const float* q        = (const float*)d_in[0];  // (8,1024,512)
    const float* k        = (const float*)d_in[1];  // (8,1024,512)
    const float* W_kernel = (const float*)d_in[2];  // (512,1536)
    const float* b_kernel = (const float*)d_in[3];  // (1536,)
    const float* W_bias   = (const float*)d_in[4];  // (512,1)
    const float* b_bias   = (const float*)d_in[5];  // (1,)
    const float* bias_b   = (const float*)d_in[6];  // (1,)
    float* out = (float*)d_out;                     // (8,1024,1024)

    // workspace carve (bytes): q_bf 8M | kp 8.03M+16K headroom | Wt 1.5M | G 24M | bias 32K
    char* ws = (char*)d_ws;
    unsigned short* q_bf = (unsigned short*)(ws);
    unsigned short* kp   = (unsigned short*)(ws + 8388608);
    unsigned short* Wt   = (unsigned short*)(ws + 8388608 + 8421376 + 16384);
    unsigned short* G    = (unsigned short*)(ws + 8388608 + 8421376 + 16384 + 1572864);
    float*          bsb  = (float*)(ws + 8388608 + 8421376 + 16384 + 1572864 + 25165824);

    cvt_all<<<4104, 256, 0, stream>>>(q, k, q_bf, kp);
    prep_Wt<<<dim3(48, 16), dim3(32, 32), 0, stream>>>(W_kernel, Wt);
    bias_kernel<<<2048, 256, 0, stream>>>(q, W_bias, b_bias, bsb);
    gemm_A<<<768, 256, 0, stream>>>(q_bf, Wt, b_kernel, G);
    gemm_B<<<1024, 256, 0, stream>>>(G, kp, bsb, bias_b, out);
}

// Round 5
// 152.039 us; speedup vs baseline: 1.1291x; 1.0003x over previous
//
#include <hip/hip_runtime.h>

// (B, Lq, Lk, D, C, KW) = (8, 1024, 1024, 512, 512, 3)

typedef __attribute__((ext_vector_type(8))) short s8vec;    // 8 x bf16 (4 VGPRs)
typedef __attribute__((ext_vector_type(4))) float floatx4;  // MFMA accumulator

__device__ __forceinline__ unsigned short f2bf(float f) {
    union { float f; unsigned u; } v; v.f = f;
    unsigned r = (v.u + 0x7FFFu + ((v.u >> 16) & 1u)) >> 16;
    return (unsigned short)r;
}

__device__ __forceinline__ void gl2lds16(const void* g, void* l) {
    __builtin_amdgcn_global_load_lds(
        (__attribute__((address_space(1))) void*)(g),
        (__attribute__((address_space(3))) void*)(l), 16, 0, 0);
}

// ---- fused: q->bf16, k->padded bf16, zero pad rows, and bias = q@W_bias+b_bias ----
__global__ void cvt_all(const float* __restrict__ q, const float* __restrict__ k,
                        unsigned short* __restrict__ qbf, unsigned short* __restrict__ kp,
                        const float* __restrict__ Wb, const float* __restrict__ b_bias,
                        float* __restrict__ biasb) {
    int blk = blockIdx.x;
    if (blk < 4104) {
        int t = blk * 256 + threadIdx.x;
        if (t < 524288) {                       // q: 8*1024*512 / 8
            const float4* p = (const float4*)q + 2 * (size_t)t;
            float4 a = p[0], b = p[1];
            union { unsigned short s[8]; uint4 v; } o;
            o.s[0]=f2bf(a.x); o.s[1]=f2bf(a.y); o.s[2]=f2bf(a.z); o.s[3]=f2bf(a.w);
            o.s[4]=f2bf(b.x); o.s[5]=f2bf(b.y); o.s[6]=f2bf(b.z); o.s[7]=f2bf(b.w);
            ((uint4*)qbf)[t] = o.v;
        } else if (t < 1048576) {               // k -> padded kp
            int e8 = t - 524288;
            size_t e = (size_t)e8 * 8;
            int b = e8 >> 16;
            int j = (e8 >> 6) & 1023;
            int c = (e8 & 63) * 8;
            const float4* p = (const float4*)(k + e);
            float4 a = p[0], bb = p[1];
            union { unsigned short s[8]; uint4 v; } o;
            o.s[0]=f2bf(a.x); o.s[1]=f2bf(a.y); o.s[2]=f2bf(a.z); o.s[3]=f2bf(a.w);
            o.s[4]=f2bf(bb.x); o.s[5]=f2bf(bb.y); o.s[6]=f2bf(bb.z); o.s[7]=f2bf(bb.w);
            *(uint4*)(kp + ((size_t)(b * 1028 + j + 1) * 512 + c)) = o.v;
        } else if (t < 1050624) {               // zero pad rows
            int z = t - 1048576;
            int b = z >> 8, r = (z >> 6) & 3, ch = z & 63;
            int row = r ? (1024 + r) : 0;
            *(uint4*)(kp + ((size_t)(b * 1028 + row) * 512 + ch * 8)) = make_uint4(0u,0u,0u,0u);
        }
    } else {                                    // bias: one wave per row
        int row  = (blk - 4104) * 4 + (threadIdx.x >> 6);
        int lane = threadIdx.x & 63;
        const float4* qr = (const float4*)(q + (size_t)row * 512) + lane * 2;
        const float4* wb = (const float4*)Wb + lane * 2;
        float4 a0 = qr[0], a1 = qr[1], b0 = wb[0], b1 = wb[1];
        float s = a0.x*b0.x + a0.y*b0.y + a0.z*b0.z + a0.w*b0.w
                + a1.x*b1.x + a1.y*b1.y + a1.z*b1.z + a1.w*b1.w;
        #pragma unroll
        for (int off = 32; off > 0; off >>= 1) s += __shfl_down(s, off);
        if (lane == 0) biasb[row] = s + b_bias[0];
    }
}

// ---- W_kernel (512 x 1536, d-major) -> Wt[w][c][d] bf16 (1536 x 512) ----
__global__ void prep_Wt(const float* __restrict__ W, unsigned short* __restrict__ Wt) {
    __shared__ float lds[32][33];
    int cw0 = blockIdx.x * 32, d0 = blockIdx.y * 32;
    int tx = threadIdx.x, ty = threadIdx.y;
    lds[ty][tx] = W[(size_t)(d0 + ty) * 1536 + cw0 + tx];
    __syncthreads();
    int cw = cw0 + ty;                 // cw = c*3 + w
    int c = cw / 3, w = cw % 3;
    Wt[((size_t)(w * 512 + c)) * 512 + d0 + tx] = f2bf(lds[tx][ty]);
}

// ---- Phase A: G[b][w][i][c] = bf16( q_bf(8192x512) @ Wt(1536x512)^T + b_kernel )
//      64m x 128n tiles, 2-wave blocks (64x64 wave-tile), grid 1536, XCD swizzle ----
__global__ __launch_bounds__(128) void gemm_A(const unsigned short* __restrict__ Abf,
                                              const unsigned short* __restrict__ Bbf,
                                              const float* __restrict__ b_kernel,
                                              unsigned short* __restrict__ G) {
    __shared__ unsigned short lds_a[64 * 32];    // 4 KB
    __shared__ unsigned short lds_b[128 * 32];   // 8 KB
    int g = blockIdx.x;                 // 0..1535
    int xcd = g & 7, slot = g >> 3;     // slot 0..191
    int i_blk = xcd * 16 + (slot & 15); // 0..127 (per-XCD 1MB q slice)
    int n_blk = slot >> 4;              // 0..11
    int i0 = i_blk * 64, n0 = n_blk * 128;
    int tid = threadIdx.x, wid = tid >> 6, lane = tid & 63;
    floatx4 acc[4][4] = {};

    for (int kk = 0; kk < 512; kk += 32) {
        #pragma unroll
        for (int s = 0; s < 6; ++s) {
            int t = s * 2 + wid;        // 0..11, wave-uniform; 16 rows per inst
            if (t < 4) {
                const unsigned short* ga = Abf + (size_t)(i0 + t * 16 + (lane >> 2)) * 512 + kk + (lane & 3) * 8;
                gl2lds16(ga, (char*)lds_a + t * 1024);
            } else {
                int u = t - 4;
                const unsigned short* gb = Bbf + (size_t)(n0 + u * 16 + (lane >> 2)) * 512 + kk + (lane & 3) * 8;
                gl2lds16(gb, (char*)lds_b + u * 1024);
            }
        }
        __syncthreads();
        int ra = lane & 15, q8 = (lane >> 4) * 8;
        s8vec af[4], bf_[4];
        #pragma unroll
        for (int mi = 0; mi < 4; mi++)
            af[mi] = *(const s8vec*)(lds_a + (mi * 16 + ra) * 32 + q8);
        #pragma unroll
        for (int ni = 0; ni < 4; ni++)
            bf_[ni] = *(const s8vec*)(lds_b + (wid * 64 + ni * 16 + ra) * 32 + q8);
        #pragma unroll
        for (int mi = 0; mi < 4; mi++)
            #pragma unroll
            for (int ni = 0; ni < 4; ni++)
                acc[mi][ni] = __builtin_amdgcn_mfma_f32_16x16x32_bf16(af[mi], bf_[ni], acc[mi][ni], 0, 0, 0);
        __syncthreads();
    }

    int cl = lane & 15, qd = lane >> 4;
    #pragma unroll
    for (int mi = 0; mi < 4; mi++) {
        #pragma unroll
        for (int ni = 0; ni < 4; ni++) {
            int n_all = n0 + wid * 64 + ni * 16 + cl;   // w*512 + c
            int c = n_all & 511, w = n_all >> 9;
            float bk = b_kernel[c * 3 + w];
            #pragma unroll
            for (int r = 0; r < 4; r++) {
                int i_g = i0 + mi * 16 + qd * 4 + r;
                int b = i_g >> 10, ii = i_g & 1023;
                G[((size_t)((b * 3 + w) * 1024 + ii)) * 512 + c] = f2bf(acc[mi][ni][r] + bk);
            }
        }
    }
}

// ---- Phase B: out[b,i,j] = sum_w sum_c G[b,w,i,c] * kp[b,j+w,c] + bias[b,i] + bias_b
//      64i x 128j tiles, 2-wave blocks (64x64 wave-tile), grid 1024,
//      XCD swizzle: xcd owns batch b (G[b] 3MB + kp[b] 1MB in its L2) ----
__global__ __launch_bounds__(128) void gemm_B(const unsigned short* __restrict__ G,
                                              const unsigned short* __restrict__ kp,
                                              const float* __restrict__ biasb,
                                              const float* __restrict__ bias_b,
                                              float* __restrict__ out) {
    __shared__ unsigned short lds_a[3 * 64 * 32];   // [w][i][c]  12 KB
    __shared__ unsigned short lds_k[144 * 32];      // 9 chunks x 16 rows  9 KB
    int g = blockIdx.x;                 // 0..1023
    int b = g & 7, slot = g >> 3;       // slot 0..127
    int j0 = (slot & 7) * 128;
    int i0 = (slot >> 3) * 64;
    int tid = threadIdx.x, wid = tid >> 6, lane = tid & 63;
    floatx4 acc[4][4] = {};
    const unsigned short* Gb  = G  + (size_t)b * 3 * 1024 * 512;
    const unsigned short* kpb = kp + (size_t)b * 1028 * 512;
    float bb = bias_b[0];

    for (int kk = 0; kk < 512; kk += 32) {
        // 21 staging chunks: 0..11 = A (w = c>>2, sub = c&3), 12..20 = k rows
        #pragma unroll
        for (int s = 0; s < 11; ++s) {
            int t = s * 2 + wid;        // wave0: evens 0..20, wave1: odds 1..19
            if (t < 21) {
                if (t < 12) {
                    int w = t >> 2, chunk = t & 3;
                    const unsigned short* ga = Gb + (size_t)(w * 1024 + i0 + chunk * 16 + (lane >> 2)) * 512
                                                  + kk + (lane & 3) * 8;
                    gl2lds16(ga, (char*)lds_a + t * 1024);
                } else {
                    int u = t - 12;     // 0..8, rows j0+u*16 .. +15
                    const unsigned short* gk = kpb + (size_t)(j0 + u * 16 + (lane >> 2)) * 512
                                                   + kk + (lane & 3) * 8;
                    gl2lds16(gk, (char*)lds_k + u * 1024);
                }
            }
        }
        __syncthreads();
        int ra = lane & 15, q8 = (lane >> 4) * 8;
        #pragma unroll
        for (int w = 0; w < 3; ++w) {
            s8vec af[4], bfr[4];
            #pragma unroll
            for (int mi = 0; mi < 4; mi++)
                af[mi] = *(const s8vec*)(lds_a + (w * 64 + mi * 16 + ra) * 32 + q8);
            #pragma unroll
            for (int ni = 0; ni < 4; ni++) {
                int rr = wid * 64 + ni * 16 + ra + w;   // lds row r = kp row j0+r
                bfr[ni] = *(const s8vec*)(lds_k + rr * 32 + q8);
            }
            #pragma unroll
            for (int mi = 0; mi < 4; mi++)
                #pragma unroll
                for (int ni = 0; ni < 4; ni++)
                    acc[mi][ni] = __builtin_amdgcn_mfma_f32_16x16x32_bf16(af[mi], bfr[ni], acc[mi][ni], 0, 0, 0);
        }
        __syncthreads();
    }

    int cl = lane & 15, qd = lane >> 4;
    #pragma unroll
    for (int mi = 0; mi < 4; mi++) {
        #pragma unroll
        for (int r = 0; r < 4; r++) {
            int i_loc = mi * 16 + qd * 4 + r;
            float bv = biasb[b * 1024 + i0 + i_loc] + bb;
            #pragma unroll
            for (int ni = 0; ni < 4; ni++) {
                int j_loc = wid * 64 + ni * 16 + cl;
                out[((size_t)(b * 1024 + i0 + i_loc)) * 1024 + j0 + j_loc] = acc[mi][ni][r] + bv;
            }
        }
    }
}

extern "C" void kernel_launch(void* const* d_in, const int* in_sizes, int n_in,
                              void* d_out, int out_size, void* d_ws, size_t ws_size,
                              hipStream_t stream) {
    const float* q        = (const float*)d_in[0];  // (8,1024,512)
    const float* k        = (const float*)d_in[1];  // (8,1024,512)
    const float* W_kernel = (const float*)d_in[2];  // (512,1536)
    const float* b_kernel = (const float*)d_in[3];  // (1536,)
    const float* W_bias   = (const float*)d_in[4];  // (512,1)
    const float* b_bias   = (const float*)d_in[5];  // (1,)
    const float* bias_b   = (const float*)d_in[6];  // (1,)
    float* out = (float*)d_out;                     // (8,1024,1024)

    // workspace carve (bytes): q_bf 8M | kp 8.03M+16K headroom | Wt 1.5M | G 24M | bias 32K
    char* ws = (char*)d_ws;
    unsigned short* q_bf = (unsigned short*)(ws);
    unsigned short* kp   = (unsigned short*)(ws + 8388608);
    unsigned short* Wt   = (unsigned short*)(ws + 8388608 + 8421376 + 16384);
    unsigned short* G    = (unsigned short*)(ws + 8388608 + 8421376 + 16384 + 1572864);
    float*          bsb  = (float*)(ws + 8388608 + 8421376 + 16384 + 1572864 + 25165824);

    cvt_all<<<6152, 256, 0, stream>>>(q, k, q_bf, kp, W_bias, b_bias, bsb);
    prep_Wt<<<dim3(48, 16), dim3(32, 32), 0, stream>>>(W_kernel, Wt);
    gemm_A<<<1536, 128, 0, stream>>>(q_bf, Wt, b_kernel, G);
    gemm_B<<<1024, 128, 0, stream>>>(G, kp, bsb, bias_b, out);
}